// Round 3
// baseline (170.961 us; speedup 1.0000x reference)
//
#include <hip/hip_runtime.h>

#define NB 8      // NUM_BLOCK
#define NT 500    // NUM_FRAME
#define NF 257    // NUM_BIN
#define NC 8      // NUM_CH
#define NNUL 4    // NUM_NULL
#define LOWF 5
#define HIGHF 70
#define NRED 65   // HIGHF-LOWF
#define S_CHUNK 16
#define WARM 16
#define K_CHUNKS 32
#define AL 0.35f

__device__ __forceinline__ float dot8(const float4& a0, const float4& a1,
                                      const float4& b0, const float4& b1) {
    return a0.x*b0.x + a0.y*b0.y + a0.z*b0.z + a0.w*b0.w
         + a1.x*b1.x + a1.y*b1.y + a1.z*b1.z + a1.w*b1.w;
}

__global__ __launch_bounds__(1024) void dcf_kernel(
    const float* __restrict__ x,           // (NB,NT,2,NF,NC) fp32
    const int* __restrict__ beam_id,       // (NB,)
    const float* __restrict__ targ_w,      // (8,2,NF,NC) fp32
    const float* __restrict__ null_w,      // (8,NNUL,2,NF,NC) fp32
    float* __restrict__ out)               // fp32: dcf (NB,NT,NF,NNUL) then targ (NB,NT,2,NF)
{
    const int tid = threadIdx.x;
    const int b = blockIdx.x & 7;
    const int k = blockIdx.x >> 3;
    const int t0 = k * S_CHUNK;
    const int te = min(NT, t0 + S_CHUNK);
    int ts = t0 - WARM; if (ts < 0) ts = 0;

    const int f = tid >> 2;    // 0..255
    const int n = tid & 3;
    const bool extra = ((tid & 63) == 0) && (tid < 256);  // lanes 0,64,128,192 handle f=256
    const int n2 = tid >> 6;

    __shared__ float xbuf[2 * NF * NC];        // 4112 floats: [p][f][c]
    __shared__ float red_phi[NRED][NNUL];
    __shared__ float red_psd[NRED];
    __shared__ float s_ratio[NNUL];
    __shared__ float s_w256[16 + 4 * 16];      // twr/twi(16), per-n nwr/nwi(16)

    const int beam = beam_id[b];

    // per-thread weights in registers
    float4 twr0, twr1, twi0, twi1, nwr0, nwr1, nwi0, nwi1;
    {
        const float* tp = targ_w + ((size_t)(beam * 2) * NF + f) * NC;
        twr0 = *(const float4*)(tp);            twr1 = *(const float4*)(tp + 4);
        twi0 = *(const float4*)(tp + NF * NC);  twi1 = *(const float4*)(tp + NF * NC + 4);
        const float* qp = null_w + ((size_t)((beam * NNUL + n) * 2) * NF + f) * NC;
        nwr0 = *(const float4*)(qp);            nwr1 = *(const float4*)(qp + 4);
        nwi0 = *(const float4*)(qp + NF * NC);  nwi1 = *(const float4*)(qp + NF * NC + 4);
    }
    // f=256 weights -> LDS
    if (tid < 16) {
        int p = tid >> 3, c = tid & 7;
        s_w256[tid] = targ_w[((size_t)(beam * 2 + p) * NF + 256) * NC + c];
    } else if (tid < 80) {
        int i = tid - 16;
        int nn = i >> 4, p = (i >> 3) & 1, c = i & 7;
        s_w256[tid] = null_w[((size_t)((beam * NNUL + nn) * 2 + p) * NF + 256) * NC + c];
    }

    float phi_r = 0.f, phi_i = 0.f, psd = 0.f;
    float phi_r2 = 0.f, phi_i2 = 0.f, psd2 = 0.f;
    const float a = AL, oma = 1.0f - AL;

    const size_t rowlen = 2 * NF * NC;  // 4112 elems
    const float* xrow = x + (size_t)(b * NT + ts) * rowlen;
    float4 pf0 = *(const float4*)(xrow + (size_t)tid * 4);
    float4 pf1 = make_float4(0.f, 0.f, 0.f, 0.f);
    if (tid < 4) pf1 = *(const float4*)(xrow + 4096 + (size_t)tid * 4);

    float* outT = out + (size_t)NB * NT * NF * NNUL;

    for (int t = ts; t < te; ++t) {
        // stage prefetched row into LDS
        *(float4*)&xbuf[tid * 4] = pf0;
        if (tid < 4) *(float4*)&xbuf[4096 + tid * 4] = pf1;
        __syncthreads();
        // prefetch next row (latency hidden behind compute)
        if (t + 1 < te) {
            const float* xr2 = x + (size_t)(b * NT + t + 1) * rowlen;
            pf0 = *(const float4*)(xr2 + (size_t)tid * 4);
            if (tid < 4) pf1 = *(const float4*)(xr2 + 4096 + (size_t)tid * 4);
        }

        // main pair (f, n)
        const float4 xr0 = *(const float4*)&xbuf[f * NC];
        const float4 xr1 = *(const float4*)&xbuf[f * NC + 4];
        const float4 xi0 = *(const float4*)&xbuf[NF * NC + f * NC];
        const float4 xi1 = *(const float4*)&xbuf[NF * NC + f * NC + 4];

        const float tr = dot8(xr0, xr1, twr0, twr1) - dot8(xi0, xi1, twi0, twi1);
        const float ti = dot8(xr0, xr1, twi0, twi1) + dot8(xi0, xi1, twr0, twr1);
        const float nr = dot8(xr0, xr1, nwr0, nwr1) - dot8(xi0, xi1, nwi0, nwi1);
        const float ni = dot8(xr0, xr1, nwi0, nwi1) + dot8(xi0, xi1, nwr0, nwr1);
        const float pw = (dot8(xr0, xr1, xr0, xr1) + dot8(xi0, xi1, xi0, xi1)) * 0.125f;

        if (t == 0) {  // exact asymmetric init from the reference (note: oma scales only the first product)
            phi_r = oma * tr * nr + ti * ni;
            phi_i = oma * ti * nr - tr * ni;
            psd   = oma * pw;
        } else {
            phi_r = a * phi_r + oma * (tr * nr + ti * ni);
            phi_i = a * phi_i + oma * (ti * nr - tr * ni);
            psd   = a * psd + oma * pw;
        }

        // extra pair (256, n2) on lanes 0/64/128/192
        float tr2 = 0.f, ti2 = 0.f;
        if (extra) {
            const float4 exr0 = *(const float4*)&xbuf[256 * NC];
            const float4 exr1 = *(const float4*)&xbuf[256 * NC + 4];
            const float4 exi0 = *(const float4*)&xbuf[NF * NC + 256 * NC];
            const float4 exi1 = *(const float4*)&xbuf[NF * NC + 256 * NC + 4];
            const float4 etwr0 = *(const float4*)&s_w256[0];
            const float4 etwr1 = *(const float4*)&s_w256[4];
            const float4 etwi0 = *(const float4*)&s_w256[8];
            const float4 etwi1 = *(const float4*)&s_w256[12];
            const float4 enwr0 = *(const float4*)&s_w256[16 + n2 * 16];
            const float4 enwr1 = *(const float4*)&s_w256[16 + n2 * 16 + 4];
            const float4 enwi0 = *(const float4*)&s_w256[16 + n2 * 16 + 8];
            const float4 enwi1 = *(const float4*)&s_w256[16 + n2 * 16 + 12];
            tr2 = dot8(exr0, exr1, etwr0, etwr1) - dot8(exi0, exi1, etwi0, etwi1);
            ti2 = dot8(exr0, exr1, etwi0, etwi1) + dot8(exi0, exi1, etwr0, etwr1);
            const float nr2 = dot8(exr0, exr1, enwr0, enwr1) - dot8(exi0, exi1, enwi0, enwi1);
            const float ni2 = dot8(exr0, exr1, enwi0, enwi1) + dot8(exi0, exi1, enwr0, enwr1);
            const float pw2 = (dot8(exr0, exr1, exr0, exr1) + dot8(exi0, exi1, exi0, exi1)) * 0.125f;
            if (t == 0) {
                phi_r2 = oma * tr2 * nr2 + ti2 * ni2;
                phi_i2 = oma * ti2 * nr2 - tr2 * ni2;
                psd2   = oma * pw2;
            } else {
                phi_r2 = a * phi_r2 + oma * (tr2 * nr2 + ti2 * ni2);
                phi_i2 = a * phi_i2 + oma * (ti2 * nr2 - tr2 * ni2);
                psd2   = a * psd2 + oma * pw2;
            }
        }

        if (t >= t0) {
            const float phi = sqrtf(phi_r * phi_r + phi_i * phi_i);
            float dcfv = fminf(fmaxf(phi / (psd + 1e-13f), 0.01f), 1.0f);
            float dcf2v = 0.f;
            if (extra) {
                const float phi2 = sqrtf(phi_r2 * phi_r2 + phi_i2 * phi_i2);
                dcf2v = fminf(fmaxf(phi2 / (psd2 + 1e-13f), 0.01f), 1.0f);
            }
            if (t > 0) {   // ratio term (t=0 output skips it, per reference)
                if (f >= LOWF && f < HIGHF) {
                    red_phi[f - LOWF][n] = phi;
                    if (n == 0) red_psd[f - LOWF] = psd;
                }
                __syncthreads();
                if (tid < 64) {
                    float s0 = 0.f, s1 = 0.f, s2 = 0.f, s3 = 0.f, sp = 0.f;
                    for (int i = tid; i < NRED; i += 64) {
                        s0 += red_phi[i][0]; s1 += red_phi[i][1];
                        s2 += red_phi[i][2]; s3 += red_phi[i][3];
                        sp += red_psd[i];
                    }
                    #pragma unroll
                    for (int off = 32; off > 0; off >>= 1) {
                        s0 += __shfl_xor(s0, off);
                        s1 += __shfl_xor(s1, off);
                        s2 += __shfl_xor(s2, off);
                        s3 += __shfl_xor(s3, off);
                        sp += __shfl_xor(sp, off);
                    }
                    if (tid < 4) {
                        float aft = (tid == 0) ? s0 : (tid == 1) ? s1 : (tid == 2) ? s2 : s3;
                        s_ratio[tid] = fminf(fmaxf(aft / (sp + 1e-10f), 0.01f), 1.0f);
                    }
                }
                __syncthreads();
                dcfv = sqrtf(dcfv * s_ratio[n]);
                if (extra) dcf2v = sqrtf(dcf2v * s_ratio[n2]);
            }
            const size_t bt = (size_t)(b * NT + t);
            out[(bt * NF + f) * NNUL + n] = dcfv;
            if (n == 0) outT[(bt * 2 + 0) * NF + f] = tr;
            if (n == 1) outT[(bt * 2 + 1) * NF + f] = ti;
            if (extra) {
                out[(bt * NF + 256) * NNUL + n2] = dcf2v;
                if (n2 == 0) outT[(bt * 2 + 0) * NF + 256] = tr2;
                if (n2 == 1) outT[(bt * 2 + 1) * NF + 256] = ti2;
            }
        }
        __syncthreads();   // protect xbuf before next staging write
    }
}

extern "C" void kernel_launch(void* const* d_in, const int* in_sizes, int n_in,
                              void* d_out, int out_size, void* d_ws, size_t ws_size,
                              hipStream_t stream) {
    const float* x       = (const float*)d_in[0];
    const int*   beam_id = (const int*)d_in[1];
    const float* targ_w  = (const float*)d_in[2];
    const float* null_w  = (const float*)d_in[3];
    float* out           = (float*)d_out;
    dcf_kernel<<<dim3(NB * K_CHUNKS), dim3(1024), 0, stream>>>(x, beam_id, targ_w, null_w, out);
}